// Round 3
// baseline (126.805 us; speedup 1.0000x reference)
//
#include <hip/hip_runtime.h>

typedef __attribute__((ext_vector_type(4))) float f32x4;
typedef __attribute__((ext_vector_type(8))) short s16x8;

#define MFMA_16x16x32_BF16 __builtin_amdgcn_mfma_f32_16x16x32_bf16

__device__ __forceinline__ unsigned short f2bf(float f) {
  unsigned int u = __builtin_bit_cast(unsigned int, f);
  unsigned int r = (u + 0x7FFFu + ((u >> 16) & 1u)) >> 16;  // RNE
  return (unsigned short)r;
}

__device__ __forceinline__ float fexp2(float x) {
#if __has_builtin(__builtin_amdgcn_exp2f)
  return __builtin_amdgcn_exp2f(x);
#else
  float r;
  asm("v_exp_f32 %0, %1" : "=v"(r) : "v"(x));
  return r;
#endif
}

#define RCP __builtin_amdgcn_rcpf
#define L2E 1.442695040888963f   // 1/ln2
#define L2E2 2.885390081777927f  // 2/ln2

// One fused persistent kernel. 512 threads = 8 waves; block owns 16 batch
// rows. Prologue: per-row attn softmax (time-invariant) + weight fragments
// fp32->bf16 into registers (4 gates x 8 kt x 16B = 128 VGPR, loaded once).
// Loop: 64 steps, ONE barrier/step via double-buffered A-tile [w_in | h]
// (16x256 bf16, XOR-swizzled). Wave w owns gate cols {g*128 + w*16 + l15},
// so i/f/g/o are lane-local. Elementwise uses fused-reciprocal exp2 forms.
__global__ __launch_bounds__(512, 2) void lstm_fused(
    const float* __restrict__ x, const float* __restrict__ Wih,
    const float* __restrict__ Whh, const float* __restrict__ bih,
    const float* __restrict__ bhh, const float* __restrict__ Wattn,
    float* __restrict__ out) {
  __shared__ __attribute__((aligned(16))) unsigned short sA[2 * 16 * 256];
  char* sAb = reinterpret_cast<char*>(sA);

  const int tid = threadIdx.x;
  const int l = tid & 63;
  const int w = tid >> 6;   // wave 0..7
  const int l15 = l & 15;
  const int khi = l >> 4;   // 0..3
  const int rowBase = blockIdx.x * 16;

  // staging/attn role: thread -> (row r_st, 4 cols at c_st)
  const int r_st = tid >> 5;          // 0..15
  const int c_st = (tid & 31) << 2;   // 0..124
  const float* xrow = x + (size_t)(rowBase + r_st) * 8192 + c_st;

  // ---- prologue 1: attn[row, c_st..+3] = softmax_d( sum_t x*wt ) ----
  float4 at;
  {
    const float wtl = Wattn[256 + l];
    float s0 = 0.f, s1 = 0.f, s2 = 0.f, s3 = 0.f;
    for (int t = 0; t < 64; ++t) {
      const float ww = __shfl(wtl, t, 64);
      const float4 v = *reinterpret_cast<const float4*>(xrow + t * 128);
      s0 = fmaf(v.x, ww, s0); s1 = fmaf(v.y, ww, s1);
      s2 = fmaf(v.z, ww, s2); s3 = fmaf(v.w, ww, s3);
    }
    // reduce over the row's 32 threads (half-wave; xor offsets < 32)
    float m = fmaxf(fmaxf(s0, s1), fmaxf(s2, s3));
#pragma unroll
    for (int off = 16; off; off >>= 1) m = fmaxf(m, __shfl_xor(m, off, 64));
    const float e0 = __expf(s0 - m), e1 = __expf(s1 - m);
    const float e2 = __expf(s2 - m), e3 = __expf(s3 - m);
    float sum = (e0 + e1) + (e2 + e3);
#pragma unroll
    for (int off = 16; off; off >>= 1) sum += __shfl_xor(sum, off, 64);
    const float inv = RCP(sum);
    at.x = e0 * inv; at.y = e1 * inv; at.z = e2 * inv; at.w = e3 * inv;
  }

  // ---- prologue 2: weight fragments into registers (once) ----
  s16x8 bfr[4][8];
  float bias2[4];
#pragma unroll
  for (int g = 0; g < 4; ++g) {
    const int col = g * 128 + w * 16 + l15;
#pragma unroll
    for (int kt = 0; kt < 8; ++kt) {
      const float* src = (kt < 4) ? (Wih + (size_t)col * 128 + kt * 32 + khi * 8)
                                  : (Whh + (size_t)col * 128 + (kt - 4) * 32 + khi * 8);
      const float4 v0 = *reinterpret_cast<const float4*>(src);
      const float4 v1 = *reinterpret_cast<const float4*>(src + 4);
      s16x8 b;
      b[0] = (short)f2bf(v0.x); b[1] = (short)f2bf(v0.y);
      b[2] = (short)f2bf(v0.z); b[3] = (short)f2bf(v0.w);
      b[4] = (short)f2bf(v1.x); b[5] = (short)f2bf(v1.y);
      b[6] = (short)f2bf(v1.z); b[7] = (short)f2bf(v1.w);
      bfr[g][kt] = b;
    }
    const float sc = (g == 2) ? L2E2 : -L2E;
    bias2[g] = sc * (bih[col] + bhh[col]);
  }

  // ---- prologue 3: stage w_in(0) + zero h into buf0; prefetch x(1) ----
  const int stg_off = r_st * 512 + ((c_st << 1) ^ ((r_st & 7) << 4));
  float4 xv = *reinterpret_cast<const float4*>(xrow);  // x(0)
  {
    ushort4 u;
    u.x = f2bf(xv.x * at.x); u.y = f2bf(xv.y * at.y);
    u.z = f2bf(xv.z * at.z); u.w = f2bf(xv.w * at.w);
    *reinterpret_cast<ushort4*>(sAb + stg_off) = u;
    const int hz = r_st * 512 + ((256 + ((tid & 31) << 3)) ^ ((r_st & 7) << 4));
    uint2 z = {0u, 0u};
    *reinterpret_cast<uint2*>(sAb + hz) = z;
  }
  xv = *reinterpret_cast<const float4*>(xrow + 128);  // x(1)

  float c4[4] = {0.f, 0.f, 0.f, 0.f};
  const char* aRdBase = sAb + l15 * 512;
  float* outP = out + (size_t)(rowBase + khi * 4) * 8192 + w * 16 + l15;
  const int hcol = 256 + ((w * 16 + l15) << 1);

  __syncthreads();

  for (int t = 0; t < 64; ++t) {
    const int cur = (t & 1) << 13;
    const int nxt = cur ^ 8192;

    // MFMA over K=256 from current A-tile
    f32x4 acc[4];
#pragma unroll
    for (int g = 0; g < 4; ++g) acc[g] = f32x4{0.f, 0.f, 0.f, 0.f};
#pragma unroll
    for (int kt = 0; kt < 8; ++kt) {
      const s16x8 af = *reinterpret_cast<const s16x8*>(
          aRdBase + cur + ((kt * 64 + khi * 16) ^ ((l15 & 7) << 4)));
#pragma unroll
      for (int g = 0; g < 4; ++g)
        acc[g] = MFMA_16x16x32_BF16(af, bfr[g][kt], acc[g], 0, 0, 0);
    }

    // stage w_in(t+1) into next buffer (independent of MFMA results)
    {
      ushort4 u;
      u.x = f2bf(xv.x * at.x); u.y = f2bf(xv.y * at.y);
      u.z = f2bf(xv.z * at.z); u.w = f2bf(xv.w * at.w);
      *reinterpret_cast<ushort4*>(sAb + nxt + stg_off) = u;
    }
    xv = *reinterpret_cast<const float4*>(xrow + ((t + 2) & 63) * 128);

    // elementwise LSTM cell (fused-reciprocal exp2 forms)
    float hreg[4];
#pragma unroll
    for (int rr = 0; rr < 4; ++rr) {
      const float Ei = fexp2(fminf(fmaf(acc[0][rr], -L2E, bias2[0]), 30.f));
      const float Ef = fexp2(fminf(fmaf(acc[1][rr], -L2E, bias2[1]), 30.f));
      const float G  = fexp2(fminf(fmaf(acc[2][rr],  L2E2, bias2[2]), 30.f));
      const float Eo = fexp2(fminf(fmaf(acc[3][rr], -L2E, bias2[3]), 30.f));
      // c' = [c*(1+Ei)(G+1) + (1+Ef)(G-1)] / [(1+Ef)(1+Ei)(G+1)]
      const float a1 = 1.f + Ei, a2 = 1.f + Ef, a3 = G + 1.f, a4 = G - 1.f;
      const float m1 = a1 * a3;
      const float num = fmaf(a2, a4, c4[rr] * m1);
      const float cn = num * RCP(a2 * m1);
      c4[rr] = cn;
      // h = (e^{2c'}-1) / [(1+Eo)(e^{2c'}+1)]
      const float C2 = fexp2(fminf(cn * L2E2, 30.f));
      const float h = (C2 - 1.f) * RCP((1.f + Eo) * (C2 + 1.f));
      hreg[rr] = h;
      outP[(size_t)rr * 8192 + t * 128] = h;
    }

    // write h(t) bf16 into next buffer's h-half
#pragma unroll
    for (int rr = 0; rr < 4; ++rr) {
      const int row = khi * 4 + rr;
      *reinterpret_cast<unsigned short*>(
          sAb + nxt + row * 512 + (hcol ^ ((row & 7) << 4))) = f2bf(hreg[rr]);
    }

    __syncthreads();  // next buffer complete; current reads done
  }
}

extern "C" void kernel_launch(void* const* d_in, const int* in_sizes, int n_in,
                              void* d_out, int out_size, void* d_ws, size_t ws_size,
                              hipStream_t stream) {
  const float* x     = (const float*)d_in[0];  // (4096, 64, 128)
  const float* W_ih  = (const float*)d_in[1];  // (512, 128)
  const float* W_hh  = (const float*)d_in[2];  // (512, 128)
  const float* b_ih  = (const float*)d_in[3];  // (512,)
  const float* b_hh  = (const float*)d_in[4];  // (512,)
  const float* Wattn = (const float*)d_in[5];  // (1, 320)
  float* out = (float*)d_out;                  // (4096, 64, 128)

  lstm_fused<<<256, 512, 0, stream>>>(x, W_ih, W_hh, b_ih, b_hh, Wattn, out);
}